// Round 3
// baseline (600.701 us; speedup 1.0000x reference)
//
#include <hip/hip_runtime.h>

#define NN 262144
#define NG 2048
#define DX 256
#define HID 256
#define BN_EPS 1e-3f

typedef float f32x4 __attribute__((ext_vector_type(4)));
typedef unsigned int u32x2 __attribute__((ext_vector_type(2)));
typedef short bf16x8 __attribute__((ext_vector_type(8)));

__device__ inline unsigned short f2bf(float f) {
  unsigned int u = __float_as_uint(f);
  u += 0x7fffu + ((u >> 16) & 1u);   // RNE (finite inputs)
  return (unsigned short)(u >> 16);
}

#if defined(__has_builtin)
#if __has_builtin(__builtin_amdgcn_cvt_pk_bf16_f32)
#define HAVE_PK_BF16 1
#endif
#endif

__device__ inline unsigned int pk2bf(float a, float b) {
#ifdef HAVE_PK_BF16
  auto t = __builtin_amdgcn_cvt_pk_bf16_f32(a, b);
  unsigned int r;
  __builtin_memcpy(&r, &t, 4);
  return r;
#else
  return (unsigned int)f2bf(a) | ((unsigned int)f2bf(b) << 16);
#endif
}

union FragU { bf16x8 v; unsigned short u[8]; unsigned int d[4]; };

// ---------------- prep ----------------
// blocks [0,2048)    : bias0''[g][:] = (gf[g]@W0b + b0)*s0 + t0   (1 graph/block)
// blocks [2048,2112) : pack W0a/W1 into frag-ordered bf16 images
// block  2112        : fold BN scale vectors
__global__ __launch_bounds__(256) void prep(
    const float* __restrict__ gf, const float* __restrict__ W0,
    const float* __restrict__ b0, const float* __restrict__ W1,
    const float* __restrict__ g0v, const float* __restrict__ be0,
    const float* __restrict__ m0v, const float* __restrict__ v0v,
    const float* __restrict__ g1v, const float* __restrict__ be1,
    const float* __restrict__ m1v, const float* __restrict__ v1v,
    const float* __restrict__ b1,
    float* __restrict__ s0v, float* __restrict__ s1v, float* __restrict__ u1v,
    float* __restrict__ bias0, unsigned short* __restrict__ wimg0,
    unsigned short* __restrict__ wimg1)
{
  const int tid = threadIdx.x;
  const int bid = blockIdx.x;
  if (bid < NG) {
    __shared__ float lgf[128];
    if (tid < 128) lgf[tid] = gf[bid * 128 + tid];
    __syncthreads();
    float acc = 0.f;
    #pragma unroll 8
    for (int k = 0; k < 128; ++k)
      acc = fmaf(lgf[k], W0[(256 + k) * 256 + tid], acc);
    float s0n = g0v[tid] * rsqrtf(v0v[tid] + BN_EPS);
    float t0n = be0[tid] - m0v[tid] * s0n;
    bias0[bid * 256 + tid] = (acc + b0[tid]) * s0n + t0n;
  } else if (bid < NG + 64) {
    __shared__ float tile[512];   // 32k x 16n
    int job0 = (bid - NG) * 4;
    for (int jj = 0; jj < 4; ++jj) {
      int job = job0 + jj;                    // (layer, cc, nt)
      int layer = job >> 7, rem = job & 127;
      int cc = rem >> 4, nt = rem & 15;
      const float* Wsrc = layer ? W1 : W0;
      unsigned short* img = layer ? wimg1 : wimg0;
      __syncthreads();
      #pragma unroll
      for (int p = 0; p < 2; ++p) {           // coalesced read
        int kl = p * 16 + (tid >> 4), nl = tid & 15;
        tile[kl * 16 + nl] = Wsrc[(cc * 32 + kl) * 256 + nt * 16 + nl];
      }
      __syncthreads();
      #pragma unroll
      for (int p = 0; p < 2; ++p) {           // frag-ordered coalesced write
        int e = p * 256 + tid;
        int ln = e >> 3, j = e & 7;
        int kl = (ln >> 4) * 8 + j, nl = ln & 15;
        img[(cc * 16 + nt) * 512 + e] = f2bf(tile[kl * 16 + nl]);
      }
    }
  } else {
    float s0n = g0v[tid] * rsqrtf(v0v[tid] + BN_EPS);
    s0v[tid] = s0n;
    float s1n = g1v[tid] * rsqrtf(v1v[tid] + BN_EPS);
    s1v[tid] = s1n;
    u1v[tid] = b1[tid] * s1n + be1[tid] - m1v[tid] * s1n;
  }
}

// ---------------- fused MLP ----------------
// D = W^T x^T: lane holds node = lane&15, feature = (lane>>4)*4+reg.
// Depth-1 software pipeline on the 12 x-loads per cc (ping-pong reg buffers),
// W1-frag double-buffer in layer 1. __launch_bounds__(256,2): 256 unified
// VGPR+AGPR budget so ALL pipeline loads stay hoisted (R2's 84-VGPR cap
// serialized them). 2 blocks/CU.
#define L0_STEP(CCUR, CNXT, XA, XB, PA, PB)                                    \
  {                                                                            \
    const bf16x8* wb = (const bf16x8*)(wimg0 + (((CCUR) * 16 + wave * 4) << 9) + lane * 8); \
    bf16x8 wf0 = wb[0], wf1 = wb[64], wf2 = wb[128], wf3 = wb[192];            \
    _Pragma("unroll")                                                          \
    for (int mt = 0; mt < 6; ++mt) {                                           \
      const float* p = xrow[mt] + (CNXT) * 32 + q * 8;                         \
      PA[mt] = *(const f32x4*)p;                                               \
      PB[mt] = *(const f32x4*)(p + 4);                                         \
    }                                                                          \
    _Pragma("unroll")                                                          \
    for (int mt = 0; mt < 6; ++mt) {                                           \
      FragU f;                                                                 \
      f.d[0] = pk2bf(XA[mt].x, XA[mt].y);                                      \
      f.d[1] = pk2bf(XA[mt].z, XA[mt].w);                                      \
      f.d[2] = pk2bf(XB[mt].x, XB[mt].y);                                      \
      f.d[3] = pk2bf(XB[mt].z, XB[mt].w);                                      \
      acc[0][mt] = __builtin_amdgcn_mfma_f32_16x16x32_bf16(wf0, f.v, acc[0][mt], 0, 0, 0); \
      acc[1][mt] = __builtin_amdgcn_mfma_f32_16x16x32_bf16(wf1, f.v, acc[1][mt], 0, 0, 0); \
      acc[2][mt] = __builtin_amdgcn_mfma_f32_16x16x32_bf16(wf2, f.v, acc[2][mt], 0, 0, 0); \
      acc[3][mt] = __builtin_amdgcn_mfma_f32_16x16x32_bf16(wf3, f.v, acc[3][mt], 0, 0, 0); \
    }                                                                          \
  }

#define L1_LOADW(CC, W)                                                        \
  {                                                                            \
    const bf16x8* wb = (const bf16x8*)(wimg1 + (((CC) * 16 + wave * 4) << 9) + lane * 8); \
    W[0] = wb[0]; W[1] = wb[64]; W[2] = wb[128]; W[3] = wb[192];               \
  }

#define L1_STEP(CC, W)                                                         \
  {                                                                            \
    bf16x8 hf[6];                                                              \
    _Pragma("unroll")                                                          \
    for (int mt = 0; mt < 6; ++mt)                                             \
      hf[mt] = *(const bf16x8*)(sH + (CC) * 3072 + mt * 512 + lane * 8);       \
    _Pragma("unroll")                                                          \
    for (int mt = 0; mt < 6; ++mt) {                                           \
      acc[0][mt] = __builtin_amdgcn_mfma_f32_16x16x32_bf16(W[0], hf[mt], acc[0][mt], 0, 0, 0); \
      acc[1][mt] = __builtin_amdgcn_mfma_f32_16x16x32_bf16(W[1], hf[mt], acc[1][mt], 0, 0, 0); \
      acc[2][mt] = __builtin_amdgcn_mfma_f32_16x16x32_bf16(W[2], hf[mt], acc[2][mt], 0, 0, 0); \
      acc[3][mt] = __builtin_amdgcn_mfma_f32_16x16x32_bf16(W[3], hf[mt], acc[3][mt], 0, 0, 0); \
    }                                                                          \
  }

__global__ __launch_bounds__(256, 2) void fused_mlp(
    const float* __restrict__ x, const int* __restrict__ bidx,
    const unsigned short* __restrict__ wimg0, const unsigned short* __restrict__ wimg1,
    const float* __restrict__ bias0, const float* __restrict__ s0v,
    const float* __restrict__ s1v, const float* __restrict__ u1v,
    const float* __restrict__ w2, float* __restrict__ out, float* __restrict__ norm)
{
  __shared__ __align__(16) unsigned short sH[24576];   // 48 KB: h1 [cc=8][mt=6][lane=64][8]
  __shared__ float zscr[384];
  __shared__ float attb[96];
  __shared__ int gb[96];

  const int tid = threadIdx.x;
  const int wave = tid >> 6, lane = tid & 63;
  const int q = lane >> 4, L = lane & 15;
  const int mbase = blockIdx.x * 96;

  int gid[6];
  const float* xrow[6];
  #pragma unroll
  for (int mt = 0; mt < 6; ++mt) {
    int node = mbase + mt * 16 + L;
    int cn = (node < NN) ? node : 0;
    gid[mt] = bidx[cn];
    xrow[mt] = x + (long)cn * DX;
  }

  f32x4 acc[4][6];
  #pragma unroll
  for (int t = 0; t < 4; ++t)
    #pragma unroll
    for (int mt = 0; mt < 6; ++mt) acc[t][mt] = (f32x4)0.0f;

  // ---- layer 0: ping-pong pipelined, no barriers ----
  f32x4 xa[6], xb[6], pa[6], pb[6];
  #pragma unroll
  for (int mt = 0; mt < 6; ++mt) {       // preload cc=0
    const float* p = xrow[mt] + q * 8;
    xa[mt] = *(const f32x4*)p;
    xb[mt] = *(const f32x4*)(p + 4);
  }
  #pragma unroll 1
  for (int cp = 0; cp < 4; ++cp) {
    int c0 = cp * 2, c1 = c0 + 1;
    int c2 = (c0 + 2 < 8) ? c0 + 2 : 7;   // clamp: tail reload stays L1-hot
    L0_STEP(c0, c1, xa, xb, pa, pb);
    L0_STEP(c1, c2, pa, pb, xa, xb);
  }

  // ---- epilogue 0: h1 = relu(acc*s0 + bias0''[g]) -> bf16 -> sH (B-frag layout) ----
  #pragma unroll
  for (int t = 0; t < 4; ++t) {
    int n0 = (wave * 4 + t) * 16 + q * 4;
    f32x4 s0q = *(const f32x4*)(s0v + n0);
    int cc = n0 >> 5, q2 = (n0 >> 3) & 3, joff = n0 & 7;
    unsigned short* dstp = sH + cc * 3072 + (q2 * 16 + L) * 8 + joff;
    #pragma unroll
    for (int mt = 0; mt < 6; ++mt) {
      f32x4 bq = *(const f32x4*)(bias0 + gid[mt] * HID + n0);
      float h0 = fmaxf(fmaf(acc[t][mt].x, s0q.x, bq.x), 0.f);
      float h1 = fmaxf(fmaf(acc[t][mt].y, s0q.y, bq.y), 0.f);
      float h2 = fmaxf(fmaf(acc[t][mt].z, s0q.z, bq.z), 0.f);
      float h3 = fmaxf(fmaf(acc[t][mt].w, s0q.w, bq.w), 0.f);
      u32x2 pk;
      pk.x = pk2bf(h0, h1);
      pk.y = pk2bf(h2, h3);
      *(u32x2*)(dstp + mt * 512) = pk;
      acc[t][mt] = (f32x4)0.0f;
    }
  }
  __syncthreads();

  // ---- layer 1: W1-frag double-buffer, sH x-frags, no barriers ----
  {
    bf16x8 wA[4], wB[4];
    L1_LOADW(0, wA);
    #pragma unroll 1
    for (int cp = 0; cp < 4; ++cp) {
      int c0 = cp * 2, c1 = c0 + 1;
      int c2 = (c0 + 2 < 8) ? c0 + 2 : 7;
      L1_LOADW(c1, wB);
      L1_STEP(c0, wA);
      L1_LOADW(c2, wA);
      L1_STEP(c1, wB);
    }
  }

  // ---- epilogue 1 + layer 2 (fp32): z = sum_n relu(acc*s1+u1)*w2 ----
  float zp[6] = {0.f, 0.f, 0.f, 0.f, 0.f, 0.f};
  #pragma unroll
  for (int t = 0; t < 4; ++t) {
    int n0 = (wave * 4 + t) * 16 + q * 4;
    f32x4 s1q = *(const f32x4*)(s1v + n0);
    f32x4 u1q = *(const f32x4*)(u1v + n0);
    f32x4 w2q = *(const f32x4*)(w2 + n0);
    #pragma unroll
    for (int mt = 0; mt < 6; ++mt) {
      float h0 = fmaxf(fmaf(acc[t][mt].x, s1q.x, u1q.x), 0.f);
      float h1 = fmaxf(fmaf(acc[t][mt].y, s1q.y, u1q.y), 0.f);
      float h2 = fmaxf(fmaf(acc[t][mt].z, s1q.z, u1q.z), 0.f);
      float h3 = fmaxf(fmaf(acc[t][mt].w, s1q.w, u1q.w), 0.f);
      zp[mt] += h0 * w2q.x + h1 * w2q.y + h2 * w2q.z + h3 * w2q.w;
    }
  }
  #pragma unroll
  for (int mt = 0; mt < 6; ++mt) {
    float z = zp[mt];
    z += __shfl_xor(z, 16, 64);
    z += __shfl_xor(z, 32, 64);
    zp[mt] = z;
  }
  if (q == 0) {
    #pragma unroll
    for (int mt = 0; mt < 6; ++mt) zscr[wave * 96 + mt * 16 + L] = zp[mt];
  }
  __syncthreads();
  if (tid < 96) {
    int node = mbase + tid;
    float z = zscr[tid] + zscr[96 + tid] + zscr[192 + tid] + zscr[288 + tid];
    float a = __expf(z);
    bool v = node < NN;
    if (v) out[node] = a;
    attb[tid] = v ? a : 0.f;
    gb[tid] = v ? bidx[node] : -1;
  }
  __syncthreads();
  if (tid < 96) {
    int g = gb[tid];
    if (g >= 0 && (tid == 0 || gb[tid - 1] != g)) {   // segment head
      float s = attb[tid];
      for (int i = tid + 1; i < 96 && gb[i] == g; ++i) s += attb[i];
      atomicAdd(&norm[g], s);
    }
  }
}

// ---------------- normalize ----------------
__global__ __launch_bounds__(256) void norm_div(float* __restrict__ out,
                                                const int* __restrict__ bidx,
                                                const float* __restrict__ norm) {
  int i = blockIdx.x * 256 + threadIdx.x;
  out[i] = out[i] / norm[bidx[i]];
}

extern "C" void kernel_launch(void* const* d_in, const int* in_sizes, int n_in,
                              void* d_out, int out_size, void* d_ws, size_t ws_size,
                              hipStream_t stream) {
  const float* x   = (const float*)d_in[0];
  const int*   bidx= (const int*)d_in[1];
  const float* gf  = (const float*)d_in[2];
  const float* W0  = (const float*)d_in[3];
  const float* b0  = (const float*)d_in[4];
  const float* W1  = (const float*)d_in[5];
  const float* b1  = (const float*)d_in[6];
  const float* W2  = (const float*)d_in[7];
  // d_in[8] = b2: cancels in att/normalizer ratio
  const float* g0v = (const float*)d_in[9];
  const float* be0 = (const float*)d_in[10];
  const float* m0v = (const float*)d_in[11];
  const float* v0v = (const float*)d_in[12];
  const float* g1v = (const float*)d_in[13];
  const float* be1 = (const float*)d_in[14];
  const float* m1v = (const float*)d_in[15];
  const float* v1v = (const float*)d_in[16];

  float* ws    = (float*)d_ws;
  float* norm  = ws;                 // 2048 f32
  float* s0v   = ws + 2048;          // 256
  float* s1v   = ws + 2304;          // 256
  float* u1v   = ws + 2560;          // 256
  float* bias0 = ws + 4096;          // 2048*256 f32 = 2 MB
  unsigned short* wimg0 = (unsigned short*)(ws + 4096 + 524288);  // 128 KB bf16
  unsigned short* wimg1 = wimg0 + 65536;                          // 128 KB bf16

  hipMemsetAsync(norm, 0, 2048 * sizeof(float), stream);
  prep<<<NG + 65, 256, 0, stream>>>(gf, W0, b0, W1, g0v, be0, m0v, v0v,
                                    g1v, be1, m1v, v1v, b1,
                                    s0v, s1v, u1v, bias0, wimg0, wimg1);
  fused_mlp<<<2731, 256, 0, stream>>>(x, bidx, wimg0, wimg1, bias0,
                                      s0v, s1v, u1v, W2, (float*)d_out, norm);
  norm_div<<<1024, 256, 0, stream>>>((float*)d_out, bidx, norm);
}

// Round 4
// 480.383 us; speedup vs baseline: 1.2505x; 1.2505x over previous
//
#include <hip/hip_runtime.h>

#define NN 262144
#define NG 2048
#define DX 256
#define HID 256
#define BN_EPS 1e-3f

typedef float f32x4 __attribute__((ext_vector_type(4)));
typedef unsigned int u32x2 __attribute__((ext_vector_type(2)));
typedef short bf16x8 __attribute__((ext_vector_type(8)));

__device__ inline unsigned short f2bf(float f) {
  unsigned int u = __float_as_uint(f);
  u += 0x7fffu + ((u >> 16) & 1u);   // RNE (finite inputs)
  return (unsigned short)(u >> 16);
}

#if defined(__has_builtin)
#if __has_builtin(__builtin_amdgcn_cvt_pk_bf16_f32)
#define HAVE_PK_BF16 1
#endif
#endif

__device__ inline unsigned int pk2bf(float a, float b) {
#ifdef HAVE_PK_BF16
  auto t = __builtin_amdgcn_cvt_pk_bf16_f32(a, b);
  unsigned int r;
  __builtin_memcpy(&r, &t, 4);
  return r;
#else
  return (unsigned int)f2bf(a) | ((unsigned int)f2bf(b) << 16);
#endif
}

union FragU { bf16x8 v; unsigned short u[8]; unsigned int d[4]; };

// async global->LDS, 16B per lane; LDS dest = wave-uniform base + lane*16
__device__ inline void dma16(const float* src, void* lds) {
  __builtin_amdgcn_global_load_lds(
      (const __attribute__((address_space(1))) unsigned int*)src,
      (__attribute__((address_space(3))) unsigned int*)lds, 16, 0, 0);
}

// ---------------- prep ----------------
// blocks [0,2048)    : bias0''[g][:] = (gf[g]@W0b + b0)*s0 + t0   (1 graph/block)
// blocks [2048,2112) : pack W0a/W1 into frag-ordered bf16 images
// block  2112        : fold BN scale vectors
__global__ __launch_bounds__(256) void prep(
    const float* __restrict__ gf, const float* __restrict__ W0,
    const float* __restrict__ b0, const float* __restrict__ W1,
    const float* __restrict__ g0v, const float* __restrict__ be0,
    const float* __restrict__ m0v, const float* __restrict__ v0v,
    const float* __restrict__ g1v, const float* __restrict__ be1,
    const float* __restrict__ m1v, const float* __restrict__ v1v,
    const float* __restrict__ b1,
    float* __restrict__ s0v, float* __restrict__ s1v, float* __restrict__ u1v,
    float* __restrict__ bias0, unsigned short* __restrict__ wimg0,
    unsigned short* __restrict__ wimg1)
{
  const int tid = threadIdx.x;
  const int bid = blockIdx.x;
  if (bid < NG) {
    __shared__ float lgf[128];
    if (tid < 128) lgf[tid] = gf[bid * 128 + tid];
    __syncthreads();
    float acc = 0.f;
    #pragma unroll 8
    for (int k = 0; k < 128; ++k)
      acc = fmaf(lgf[k], W0[(256 + k) * 256 + tid], acc);
    float s0n = g0v[tid] * rsqrtf(v0v[tid] + BN_EPS);
    float t0n = be0[tid] - m0v[tid] * s0n;
    bias0[bid * 256 + tid] = (acc + b0[tid]) * s0n + t0n;
  } else if (bid < NG + 64) {
    __shared__ float tile[512];   // 32k x 16n
    int job0 = (bid - NG) * 4;
    for (int jj = 0; jj < 4; ++jj) {
      int job = job0 + jj;                    // (layer, cc, nt)
      int layer = job >> 7, rem = job & 127;
      int cc = rem >> 4, nt = rem & 15;
      const float* Wsrc = layer ? W1 : W0;
      unsigned short* img = layer ? wimg1 : wimg0;
      __syncthreads();
      #pragma unroll
      for (int p = 0; p < 2; ++p) {           // coalesced read
        int kl = p * 16 + (tid >> 4), nl = tid & 15;
        tile[kl * 16 + nl] = Wsrc[(cc * 32 + kl) * 256 + nt * 16 + nl];
      }
      __syncthreads();
      #pragma unroll
      for (int p = 0; p < 2; ++p) {           // frag-ordered coalesced write
        int e = p * 256 + tid;
        int ln = e >> 3, j = e & 7;
        int kl = (ln >> 4) * 8 + j, nl = ln & 15;
        img[(cc * 16 + nt) * 512 + e] = f2bf(tile[kl * 16 + nl]);
      }
    }
  } else {
    float s0n = g0v[tid] * rsqrtf(v0v[tid] + BN_EPS);
    s0v[tid] = s0n;
    float s1n = g1v[tid] * rsqrtf(v1v[tid] + BN_EPS);
    s1v[tid] = s1n;
    u1v[tid] = b1[tid] * s1n + be1[tid] - m1v[tid] * s1n;
  }
}

// ---------------- fused MLP ----------------
// x staged block-cooperatively via global_load_lds in 24KB quarters (double
// buffered; DMA for Q(n+1) issued right after the barrier, ahead of compute on
// Qn, so the next barrier's vmcnt drain overlaps a full compute phase).
// LDS granule layouts XOR-swizzled for conflict-free b128 reads:
//   x  : granule(R, gk) at R*16 + (gk ^ (R&3))   [16B granules, 16/row-quarter]
//   h1 : granule(R, gk) at R*32 + (gk ^ (R&7))   [re-uses the same 48KB]
// 51.4KB LDS -> 3 blocks/CU; no per-wave global x loads at all.
#define L0_PAIR(BUFOFF, CC0)                                                   \
  {                                                                            \
    _Pragma("unroll")                                                          \
    for (int cl = 0; cl < 2; ++cl) {                                           \
      int cc = (CC0) + cl;                                                     \
      const bf16x8* wb = (const bf16x8*)(wimg0 + ((cc * 16 + wave * 4) << 9) + lane * 8); \
      bf16x8 wf0 = wb[0], wf1 = wb[64], wf2 = wb[128], wf3 = wb[192];          \
      int gkb = ((cl * 8 + q * 2) ^ sw3) << 4;                                 \
      _Pragma("unroll")                                                        \
      for (int mt = 0; mt < 6; ++mt) {                                         \
        const unsigned char* pbase = sX + (BUFOFF) + (mt * 16 + L) * 256;      \
        f32x4 va = *(const f32x4*)(pbase + gkb);                               \
        f32x4 vb = *(const f32x4*)(pbase + (gkb ^ 16));                        \
        FragU f;                                                               \
        f.d[0] = pk2bf(va.x, va.y); f.d[1] = pk2bf(va.z, va.w);                \
        f.d[2] = pk2bf(vb.x, vb.y); f.d[3] = pk2bf(vb.z, vb.w);                \
        acc[0][mt] = __builtin_amdgcn_mfma_f32_16x16x32_bf16(wf0, f.v, acc[0][mt], 0, 0, 0); \
        acc[1][mt] = __builtin_amdgcn_mfma_f32_16x16x32_bf16(wf1, f.v, acc[1][mt], 0, 0, 0); \
        acc[2][mt] = __builtin_amdgcn_mfma_f32_16x16x32_bf16(wf2, f.v, acc[2][mt], 0, 0, 0); \
        acc[3][mt] = __builtin_amdgcn_mfma_f32_16x16x32_bf16(wf3, f.v, acc[3][mt], 0, 0, 0); \
      }                                                                        \
    }                                                                          \
  }

__global__ __launch_bounds__(256, 3) void fused_mlp(
    const float* __restrict__ x, const int* __restrict__ bidx,
    const unsigned short* __restrict__ wimg0, const unsigned short* __restrict__ wimg1,
    const float* __restrict__ bias0, const float* __restrict__ s0v,
    const float* __restrict__ s1v, const float* __restrict__ u1v,
    const float* __restrict__ w2, float* __restrict__ out, float* __restrict__ norm)
{
  __shared__ __align__(16) unsigned char sX[49152];  // Q-buf A/B; later h1 (48KB)
  __shared__ float zscr[384];
  __shared__ float attb[96];
  __shared__ int gb[96];

  const int tid = threadIdx.x;
  const int wave = tid >> 6, lane = tid & 63;
  const int q = lane >> 4, L = lane & 15;
  const int sw3 = L & 3, sw7 = L & 7;
  const int mbase = blockIdx.x * 96;

  // DMA lane geometry: 4 rows x 16 granules per instruction, 6 inst/wave/quarter
  const int dRl = lane >> 4;            // row within inst
  const int dgk = (lane & 15) ^ dRl;    // swizzled source granule (R&3 == dRl)

  int gid[6];
  #pragma unroll
  for (int mt = 0; mt < 6; ++mt) {
    int node = mbase + mt * 16 + L;
    gid[mt] = bidx[(node < NN) ? node : 0];
  }

  // ---- stage quarter 0 into buf A ----
  #pragma unroll
  for (int i = 0; i < 6; ++i) {
    int j = wave * 6 + i;
    int node = mbase + j * 4 + dRl;
    node = (node < NN) ? node : (NN - 1);
    dma16(x + (long)node * 256 + dgk * 4, sX + j * 1024);
  }

  f32x4 acc[4][6];
  #pragma unroll
  for (int t = 0; t < 4; ++t)
    #pragma unroll
    for (int mt = 0; mt < 6; ++mt) acc[t][mt] = (f32x4)0.0f;

  __syncthreads();                                   // Q0 landed
  // stage Q1 -> B, compute Q0 (cc 0-1)
  #pragma unroll
  for (int i = 0; i < 6; ++i) {
    int j = wave * 6 + i;
    int node = mbase + j * 4 + dRl;
    node = (node < NN) ? node : (NN - 1);
    dma16(x + (long)node * 256 + 64 + dgk * 4, sX + 24576 + j * 1024);
  }
  L0_PAIR(0, 0)
  __syncthreads();                                   // Q1 landed, A free
  // stage Q2 -> A, compute Q1 (cc 2-3)
  #pragma unroll
  for (int i = 0; i < 6; ++i) {
    int j = wave * 6 + i;
    int node = mbase + j * 4 + dRl;
    node = (node < NN) ? node : (NN - 1);
    dma16(x + (long)node * 256 + 128 + dgk * 4, sX + j * 1024);
  }
  L0_PAIR(24576, 2)
  __syncthreads();                                   // Q2 landed, B free
  // stage Q3 -> B, compute Q2 (cc 4-5)
  #pragma unroll
  for (int i = 0; i < 6; ++i) {
    int j = wave * 6 + i;
    int node = mbase + j * 4 + dRl;
    node = (node < NN) ? node : (NN - 1);
    dma16(x + (long)node * 256 + 192 + dgk * 4, sX + 24576 + j * 1024);
  }
  L0_PAIR(0, 4)
  __syncthreads();                                   // Q3 landed
  L0_PAIR(24576, 6)
  __syncthreads();                                   // all x reads done; sX reusable

  // ---- epilogue 0: h1 = relu(acc*s0 + bias0''[g]) -> bf16 -> sX as h1 ----
  #pragma unroll
  for (int t = 0; t < 4; ++t) {
    int n0 = (wave * 4 + t) * 16 + q * 4;
    f32x4 s0q = *(const f32x4*)(s0v + n0);
    int gwb = ((n0 >> 3) ^ sw7) << 4;
    int boff = (q & 1) << 3;
    #pragma unroll
    for (int mt = 0; mt < 6; ++mt) {
      f32x4 bq = *(const f32x4*)(bias0 + gid[mt] * HID + n0);
      float h0 = fmaxf(fmaf(acc[t][mt].x, s0q.x, bq.x), 0.f);
      float h1 = fmaxf(fmaf(acc[t][mt].y, s0q.y, bq.y), 0.f);
      float h2 = fmaxf(fmaf(acc[t][mt].z, s0q.z, bq.z), 0.f);
      float h3 = fmaxf(fmaf(acc[t][mt].w, s0q.w, bq.w), 0.f);
      u32x2 pk;
      pk.x = pk2bf(h0, h1);
      pk.y = pk2bf(h2, h3);
      *(u32x2*)(sX + (mt * 16 + L) * 512 + gwb + boff) = pk;
      acc[t][mt] = (f32x4)0.0f;
    }
  }
  __syncthreads();

  // ---- layer 1: h1 frags from LDS (swizzled), W1 frags from global ----
  #pragma unroll 1
  for (int cc = 0; cc < 8; ++cc) {
    const bf16x8* wb = (const bf16x8*)(wimg1 + ((cc * 16 + wave * 4) << 9) + lane * 8);
    bf16x8 wf0 = wb[0], wf1 = wb[64], wf2 = wb[128], wf3 = wb[192];
    int g1b = ((cc * 4 + q) ^ sw7) << 4;
    #pragma unroll
    for (int mt = 0; mt < 6; ++mt) {
      bf16x8 hf = *(const bf16x8*)(sX + (mt * 16 + L) * 512 + g1b);
      acc[0][mt] = __builtin_amdgcn_mfma_f32_16x16x32_bf16(wf0, hf, acc[0][mt], 0, 0, 0);
      acc[1][mt] = __builtin_amdgcn_mfma_f32_16x16x32_bf16(wf1, hf, acc[1][mt], 0, 0, 0);
      acc[2][mt] = __builtin_amdgcn_mfma_f32_16x16x32_bf16(wf2, hf, acc[2][mt], 0, 0, 0);
      acc[3][mt] = __builtin_amdgcn_mfma_f32_16x16x32_bf16(wf3, hf, acc[3][mt], 0, 0, 0);
    }
  }

  // ---- epilogue 1 + layer 2 (fp32): z = sum_n relu(acc*s1+u1)*w2 ----
  float zp[6] = {0.f, 0.f, 0.f, 0.f, 0.f, 0.f};
  #pragma unroll
  for (int t = 0; t < 4; ++t) {
    int n0 = (wave * 4 + t) * 16 + q * 4;
    f32x4 s1q = *(const f32x4*)(s1v + n0);
    f32x4 u1q = *(const f32x4*)(u1v + n0);
    f32x4 w2q = *(const f32x4*)(w2 + n0);
    #pragma unroll
    for (int mt = 0; mt < 6; ++mt) {
      float h0 = fmaxf(fmaf(acc[t][mt].x, s1q.x, u1q.x), 0.f);
      float h1 = fmaxf(fmaf(acc[t][mt].y, s1q.y, u1q.y), 0.f);
      float h2 = fmaxf(fmaf(acc[t][mt].z, s1q.z, u1q.z), 0.f);
      float h3 = fmaxf(fmaf(acc[t][mt].w, s1q.w, u1q.w), 0.f);
      zp[mt] += h0 * w2q.x + h1 * w2q.y + h2 * w2q.z + h3 * w2q.w;
    }
  }
  #pragma unroll
  for (int mt = 0; mt < 6; ++mt) {
    float z = zp[mt];
    z += __shfl_xor(z, 16, 64);
    z += __shfl_xor(z, 32, 64);
    zp[mt] = z;
  }
  if (q == 0) {
    #pragma unroll
    for (int mt = 0; mt < 6; ++mt) zscr[wave * 96 + mt * 16 + L] = zp[mt];
  }
  __syncthreads();
  if (tid < 96) {
    int node = mbase + tid;
    float z = zscr[tid] + zscr[96 + tid] + zscr[192 + tid] + zscr[288 + tid];
    float a = __expf(z);
    bool v = node < NN;
    if (v) out[node] = a;
    attb[tid] = v ? a : 0.f;
    gb[tid] = v ? bidx[node] : -1;
  }
  __syncthreads();
  if (tid < 96) {
    int g = gb[tid];
    if (g >= 0 && (tid == 0 || gb[tid - 1] != g)) {   // segment head
      float s = attb[tid];
      for (int i = tid + 1; i < 96 && gb[i] == g; ++i) s += attb[i];
      atomicAdd(&norm[g], s);
    }
  }
}

// ---------------- normalize ----------------
__global__ __launch_bounds__(256) void norm_div(float* __restrict__ out,
                                                const int* __restrict__ bidx,
                                                const float* __restrict__ norm) {
  int i = blockIdx.x * 256 + threadIdx.x;
  out[i] = out[i] / norm[bidx[i]];
}

extern "C" void kernel_launch(void* const* d_in, const int* in_sizes, int n_in,
                              void* d_out, int out_size, void* d_ws, size_t ws_size,
                              hipStream_t stream) {
  const float* x   = (const float*)d_in[0];
  const int*   bidx= (const int*)d_in[1];
  const float* gf  = (const float*)d_in[2];
  const float* W0  = (const float*)d_in[3];
  const float* b0  = (const float*)d_in[4];
  const float* W1  = (const float*)d_in[5];
  const float* b1  = (const float*)d_in[6];
  const float* W2  = (const float*)d_in[7];
  // d_in[8] = b2: cancels in att/normalizer ratio
  const float* g0v = (const float*)d_in[9];
  const float* be0 = (const float*)d_in[10];
  const float* m0v = (const float*)d_in[11];
  const float* v0v = (const float*)d_in[12];
  const float* g1v = (const float*)d_in[13];
  const float* be1 = (const float*)d_in[14];
  const float* m1v = (const float*)d_in[15];
  const float* v1v = (const float*)d_in[16];

  float* ws    = (float*)d_ws;
  float* norm  = ws;                 // 2048 f32
  float* s0v   = ws + 2048;          // 256
  float* s1v   = ws + 2304;          // 256
  float* u1v   = ws + 2560;          // 256
  float* bias0 = ws + 4096;          // 2048*256 f32 = 2 MB
  unsigned short* wimg0 = (unsigned short*)(ws + 4096 + 524288);  // 128 KB bf16
  unsigned short* wimg1 = wimg0 + 65536;                          // 128 KB bf16

  hipMemsetAsync(norm, 0, 2048 * sizeof(float), stream);
  prep<<<NG + 65, 256, 0, stream>>>(gf, W0, b0, W1, g0v, be0, m0v, v0v,
                                    g1v, be1, m1v, v1v, b1,
                                    s0v, s1v, u1v, bias0, wimg0, wimg1);
  fused_mlp<<<2731, 256, 0, stream>>>(x, bidx, wimg0, wimg1, bias0,
                                      s0v, s1v, u1v, W2, (float*)d_out, norm);
  norm_div<<<1024, 256, 0, stream>>>((float*)d_out, bidx, norm);
}